// Round 9
// baseline (22.027 us; speedup 1.0000x reference)
//
#include <hip/hip_runtime.h>

// Ray-AABB nearest intersection. R rays x B boxes.
// Outputs (float32, concatenated): [0,R) = nearest box idx (or -1), [R,2R) = distance (or -1).
//
// Bit-exactness with the numpy reference (argmin index output) is preserved by:
//  - divisions == IEEE RN division: hoist y = RN(1/rd) once per ray/axis (exact div),
//    then Markstein per box: q0=RN(a*y); e=FMA(-b*q0 + a) [exact residual, computed
//    as fma(rd, -q0, a) -- identical product]; q=RN(q0+e*y) == RN(a/b).
//    v_pk_* ops are elementwise IEEE RN, same as scalar (validated R8, absmax 0.0)
//  - p = ro + t*rd under `#pragma clang fp contract(off)`: separate mul/add roundings
//  - argmin first-occurrence: 4 lanes/ray scan 8 boxes each; cross-lane reduce is
//    lexicographic min on (t, box_idx)  == np.argmin first-min semantics
//  - own-axis in-band check elided (validated absmax 0.0 since R4)
//
// Perf: R5..R8 all ~22-24us => latency coverage never improved; hypothesis: VGPR
// landed in 65..128 band -> stuck at 4 waves/SIMD. This round shrinks NATURAL
// register demand (8 boxes/thread, unroll 2, ~50 VGPR est.) to cross the <=64
// threshold -> 8 waves/SIMD. (R6 lesson: do NOT force via launch_bounds -> spills.)
// LDS: boxes stored slot-permuted so the 4 par-partner addresses are 48B apart
// (disjoint banks) instead of 384B (same banks, 4-way conflict).

typedef float v2f __attribute__((ext_vector_type(2)));

constexpr int BMAX    = 32;
constexpr int NSPLIT  = 4;            // threads per ray
constexpr int BPT     = BMAX / NSPLIT; // boxes per thread = 8

__global__ __launch_bounds__(256) void ray_aabb_kernel(
    const float* __restrict__ rays_o,
    const float* __restrict__ rays_d,
    const float* __restrict__ bbox,
    float* __restrict__ out_idx,
    float* __restrict__ out_dist,
    int R)
{
    const float BIG = 10000000000.0f;
    const float EPS = 1e-4f;

    // Slot s holds box b = (s&3)*BPT + (s>>2)  (par-partners adjacent -> bank-disjoint).
    // Per slot: q0=(lo0,hi0,lo1,hi1)  q1=(lo2,hi2,loE0,loE1)  q2=(loE2,hiE0,hiE1,hiE2)
    __shared__ float4 s_q[BMAX][3];

    int t = threadIdx.x;
    if (t < BMAX) {
        int slot = t;
        int b = (slot & 3) * BPT + (slot >> 2);
        float lo[3], hi[3], loE[3], hiE[3];
        #pragma unroll
        for (int a = 0; a < 3; ++a) {
            float c = bbox[b * 6 + a];
            float s = bbox[b * 6 + 3 + a];
            float h  = __fmul_rn(s, 0.5f);
            lo[a]  = __fsub_rn(c, h);
            hi[a]  = __fadd_rn(c, h);
            loE[a] = __fsub_rn(lo[a], EPS);
            hiE[a] = __fadd_rn(hi[a], EPS);
        }
        s_q[slot][0] = make_float4(lo[0], hi[0], lo[1], hi[1]);
        s_q[slot][1] = make_float4(lo[2], hi[2], loE[0], loE[1]);
        s_q[slot][2] = make_float4(loE[2], hiE[0], hiE[1], hiE[2]);
    }
    __syncthreads();

    // 4 threads per ray: par selects an 8-box strip.
    int gid = blockIdx.x * blockDim.x + threadIdx.x;
    int ray = gid >> 2;
    int par = gid & 3;           // boxes [par*8, par*8+8)
    if (ray >= R) return;

    float ro[3], rd[3], y[3];
    #pragma unroll
    for (int a = 0; a < 3; ++a) {
        ro[a] = rays_o[ray * 3 + a];
        float d = rays_d[ray * 3 + a];
        rd[a] = (d == 0.0f) ? 1e-8f : d;
        y[a]  = __fdiv_rn(1.0f, rd[a]);   // exact RN reciprocal (Markstein precondition)
    }

    bool  keep  = false;
    float best  = __builtin_inff();  // BIG < inf -> first scanned box claims when all BIG
    int   bestb = par * BPT;

    #pragma unroll 2
    for (int bi = 0; bi < BPT; ++bi) {
        int slot = bi * 4 + par;
        int b    = par * BPT + bi;     // true box index
        float4 q0 = s_q[slot][0];
        float4 q1 = s_q[slot][1];
        float4 q2 = s_q[slot][2];
        v2f bnd[3];                    // {lo,hi} per axis, adjacent pairs from b128 loads
        bnd[0] = v2f{q0.x, q0.y};
        bnd[1] = v2f{q0.z, q0.w};
        bnd[2] = v2f{q1.x, q1.y};
        float loE[3] = {q1.z, q1.w, q2.x};
        float hiE[3] = {q2.y, q2.z, q2.w};

        float entry[3], exitv[3];
        #pragma unroll
        for (int a = 0; a < 3; ++a) {
            // Packed Markstein: both bounds' divisions in one chain of pk ops.
            v2f ys  = v2f{y[a], y[a]};
            v2f rs  = v2f{rd[a], rd[a]};
            v2f d2  = bnd[a] - v2f{ro[a], ro[a]};               // pk sub
            v2f q0v = d2 * ys;                                   // pk mul
            v2f e   = __builtin_elementwise_fma(rs, -q0v, d2);   // pk fma (exact residual)
            v2f qv  = __builtin_elementwise_fma(e, ys, q0v);     // pk fma == RN(d2/rd)
            entry[a] = fminf(qv.x, qv.y);
            exitv[a] = fmaxf(qv.x, qv.y);
        }
        float tmm = fmaxf(entry[0], fmaxf(entry[1], entry[2]));
        float tmx = fminf(exitv[0], fminf(exitv[1], exitv[2]));
        keep = keep || ((tmm < tmx) && (tmx > 0.0f));

        // Candidate validity: for axis a, in-band at the two OTHER candidates (packed).
        bool inb[3][3];
        #pragma unroll
        for (int a = 0; a < 3; ++a) {
            int o1 = (a == 0) ? 1 : 0;
            int o2 = (a == 2) ? 1 : 2;
            v2f tc2 = v2f{entry[o1], entry[o2]};
            {
                #pragma clang fp contract(off)
                v2f m2 = tc2 * v2f{rd[a], rd[a]};                // pk mul (rounded)
                v2f p2 = v2f{ro[a], ro[a]} + m2;                 // pk add (rounded)
                inb[a][o1] = (p2.x >= loE[a]) && (p2.x <= hiE[a]);
                inb[a][o2] = (p2.y >= loE[a]) && (p2.y <= hiE[a]);
            }
        }
        float tn = BIG;
        #pragma unroll
        for (int cnd = 0; cnd < 3; ++cnd) {
            int a1 = (cnd == 0) ? 1 : 0;
            int a2 = (cnd == 2) ? 1 : 2;
            bool v = (entry[cnd] >= 0.0f) && inb[a1][cnd] && inb[a2][cnd];
            if (v) tn = fminf(tn, entry[cnd]);
        }
        if (tn < best) { best = tn; bestb = b; }  // strict <: first-min within strip
    }

    // 4-lane reduce: lexicographic min on (best, bestb) == global first-occurrence
    // argmin; OR for keep.
    #pragma unroll
    for (int mask = 1; mask <= 2; mask <<= 1) {
        float ob  = __shfl_xor(best, mask, 64);
        int   obb = __shfl_xor(bestb, mask, 64);
        int   ok  = __shfl_xor((int)keep, mask, 64);
        if (ob < best || (ob == best && obb < bestb)) { best = ob; bestb = obb; }
        keep = keep || (ok != 0);
    }

    if (par == 0) {
        out_idx[ray]  = keep ? (float)bestb : -1.0f;
        out_dist[ray] = keep ? best : -1.0f;
    }
}

extern "C" void kernel_launch(void* const* d_in, const int* in_sizes, int n_in,
                              void* d_out, int out_size, void* d_ws, size_t ws_size,
                              hipStream_t stream) {
    const float* rays_o = (const float*)d_in[0];
    const float* rays_d = (const float*)d_in[1];
    const float* bbox   = (const float*)d_in[2];
    int R = in_sizes[0] / 3;

    float* out = (float*)d_out;
    float* out_idx  = out;
    float* out_dist = out + R;

    const int threads = 256;
    const long long total = (long long)NSPLIT * R;   // 4 threads per ray
    const int blocks = (int)((total + threads - 1) / threads);
    ray_aabb_kernel<<<blocks, threads, 0, stream>>>(rays_o, rays_d, bbox,
                                                    out_idx, out_dist, R);
}